// Round 1
// baseline (5854.993 us; speedup 1.0000x reference)
//
#include <hip/hip_runtime.h>
#include <hip/hip_bf16.h>
#include <stdint.h>

#define B_SZ 2048
#define H_SZ 1024
#define S_SZ 128
#define G4   4096

typedef short short8 __attribute__((ext_vector_type(8)));
typedef float floatx4 __attribute__((ext_vector_type(4)));

#define AS1 __attribute__((address_space(1)))
#define AS3 __attribute__((address_space(3)))

// Persistent device buffers (fully rewritten on every kernel_launch call).
__device__ ushort g_Wp[G4 * H_SZ];       // packed W_hh, bf16: row j = (h/16)*64 + gate*16 + (h%16)
__device__ ushort g_h[2][B_SZ * H_SZ];   // hidden state ping-pong, bf16
__device__ float  g_c[B_SZ * H_SZ];      // cell state, fp32
__device__ float  g_wih[G4];             // packed W_ih
__device__ float  g_bias[G4];            // packed (b_ih + b_hh)

__device__ __forceinline__ float bf2f(ushort u) {
  return __uint_as_float(((unsigned)u) << 16);
}
__device__ __forceinline__ ushort f2bf(float f) {
  unsigned u = __float_as_uint(f);
  return (ushort)((u + 0x7FFFu + ((u >> 16) & 1u)) >> 16);
}
__device__ __forceinline__ float fsig(float x) { return 1.f / (1.f + __expf(-x)); }
__device__ __forceinline__ float ftanh(float x) { return 1.f - 2.f / (__expf(2.f * x) + 1.f); }

__device__ __forceinline__ void gload16(const void* g, void* l) {
  __builtin_amdgcn_global_load_lds((const AS1 void*)g, (AS3 void*)l, 16, 0, 0);
}

// ---------------- prep kernels ----------------

__global__ __launch_bounds__(256) void prep_wpack(const float* __restrict__ Whh) {
  const int gid = blockIdx.x * 256 + threadIdx.x;  // 524288 total
  const int j   = gid >> 7;                        // packed row 0..4095
  const int c8  = (gid & 127) << 3;                // k offset
  const int gate = (j >> 4) & 3;
  const int h    = ((j >> 6) << 4) | (j & 15);
  const float* src = Whh + (size_t)(gate * H_SZ + h) * H_SZ + c8;
  floatx4 a = *(const floatx4*)src;
  floatx4 b = *(const floatx4*)(src + 4);
  short8 o;
#pragma unroll
  for (int i = 0; i < 4; ++i) o[i] = (short)f2bf(a[i]);
#pragma unroll
  for (int i = 0; i < 4; ++i) o[4 + i] = (short)f2bf(b[i]);
  *(short8*)&g_Wp[(size_t)j * H_SZ + c8] = o;
}

__global__ __launch_bounds__(256) void prep_misc(const float* __restrict__ Wih,
                                                 const float* __restrict__ bih,
                                                 const float* __restrict__ bhh) {
  const int j = blockIdx.x * 256 + threadIdx.x;  // 4096
  const int gate = (j >> 4) & 3;
  const int h    = ((j >> 6) << 4) | (j & 15);
  const int jp   = gate * H_SZ + h;
  g_wih[j]  = Wih[jp];
  g_bias[j] = bih[jp] + bhh[jp];
}

__global__ __launch_bounds__(256) void prep_state(const float* __restrict__ hidden,
                                                  const float* __restrict__ cell) {
  const int gid = blockIdx.x * 256 + threadIdx.x;  // 262144
  const int o8  = gid << 3;
  short8 o;
#pragma unroll
  for (int i = 0; i < 8; ++i) o[i] = (short)f2bf(hidden[o8 + i]);
  *(short8*)&g_h[0][o8] = o;
  floatx4 c0 = *(const floatx4*)&cell[o8];
  floatx4 c1 = *(const floatx4*)&cell[o8 + 4];
  *(floatx4*)&g_c[o8]     = c0;
  *(floatx4*)&g_c[o8 + 4] = c1;
}

// ---------------- main step kernel ----------------
// grid (32, 16): blockIdx.x = jt (column tile of 128 packed gate-cols = 32 h),
//                blockIdx.y = bt (row tile of 128 batch rows)
__global__ __launch_bounds__(256, 2)
void lstm_step(int t, int p,
               const float* __restrict__ wfc_prev,  // W_fc[t-1] row (valid when t>0)
               const float* __restrict__ bfc_prev,  // &b_fc[t-1]
               float* __restrict__ out) {
  __shared__ ushort Alds[128 * 32];
  __shared__ ushort Blds[128 * 32];
  __shared__ float wfc_s[32];
  __shared__ float xred[256];
  __shared__ float xbuf[128];

  const ushort* __restrict__ hin = g_h[p];
  ushort* __restrict__ hout      = g_h[p ^ 1];

  const int tid  = threadIdx.x;
  const int lane = tid & 63;
  const int wid  = tid >> 6;
  const int jt   = blockIdx.x;
  const int brow = blockIdx.y << 7;
  const int jcol = jt << 7;

  const int wr = wid >> 1, wc = wid & 1;
  const int lr = lane & 15, lk = lane >> 4;

  floatx4 acc[4][4];
#pragma unroll
  for (int m = 0; m < 4; ++m)
#pragma unroll
    for (int n = 0; n < 4; ++n) acc[m][n] = {0.f, 0.f, 0.f, 0.f};

  float xacc = 0.f;
  const int srow  = lane >> 2;
  const int skq   = (lane & 3) * 8;
  const int prow  = tid & 127;
  const int phalf = tid >> 7;

  for (int kk = 0; kk < 32; ++kk) {
    const int kbase = kk * 32 + skq;
    // stage A (h) and B (packed W) tiles: 128x32 bf16 each, direct-to-LDS
    gload16(hin + (size_t)(brow + wid * 16 + srow) * H_SZ + kbase, &Alds[wid * 512]);
    gload16(hin + (size_t)(brow + (wid + 4) * 16 + srow) * H_SZ + kbase, &Alds[(wid + 4) * 512]);
    gload16(g_Wp + (size_t)(jcol + wid * 16 + srow) * H_SZ + kbase, &Blds[wid * 512]);
    gload16(g_Wp + (size_t)(jcol + (wid + 4) * 16 + srow) * H_SZ + kbase, &Blds[(wid + 4) * 512]);
    if (t > 0 && tid < 32) wfc_s[tid] = wfc_prev[kk * 32 + tid];
    __syncthreads();

    short8 a[4], b[4];
#pragma unroll
    for (int m = 0; m < 4; ++m)
      a[m] = *(const short8*)&Alds[(wr * 64 + m * 16 + lr) * 32 + lk * 8];
#pragma unroll
    for (int n = 0; n < 4; ++n)
      b[n] = *(const short8*)&Blds[(wc * 64 + n * 16 + lr) * 32 + lk * 8];
#pragma unroll
    for (int m = 0; m < 4; ++m)
#pragma unroll
      for (int n = 0; n < 4; ++n)
        acc[m][n] = __builtin_amdgcn_mfma_f32_16x16x32_bf16(a[m], b[n], acc[m][n], 0, 0, 0);

    // fused head: partial dot of h_{t-1} rows with W_fc[t-1]
    if (t > 0) {
      short8 v0 = *(const short8*)&Alds[prow * 32 + phalf * 16];
      short8 v1 = *(const short8*)&Alds[prow * 32 + phalf * 16 + 8];
#pragma unroll
      for (int i = 0; i < 8; ++i) xacc += bf2f((ushort)v0[i]) * wfc_s[phalf * 16 + i];
#pragma unroll
      for (int i = 0; i < 8; ++i) xacc += bf2f((ushort)v1[i]) * wfc_s[phalf * 16 + 8 + i];
    }
    __syncthreads();
  }

  if (t > 0) {
    xred[tid] = xacc;
    __syncthreads();
    if (tid < 128) {
      float pr = xred[tid] + xred[tid + 128] + bfc_prev[0];
      xbuf[tid] = pr;
      if (jt == 0) out[(size_t)(brow + tid) * S_SZ + (t - 1)] = pr;
    }
    __syncthreads();
  }

  // epilogue: fragment n == gate n (i,f,g,o) for the same (row, h) per lane
  const int hcol = ((jt * 2 + wc) << 4) + lr;  // global h index 0..1023
  float wih[4], bb[4];
#pragma unroll
  for (int n = 0; n < 4; ++n) {
    const int col = jcol + wc * 64 + n * 16 + lr;
    wih[n] = g_wih[col];
    bb[n]  = g_bias[col];
  }
#pragma unroll
  for (int m = 0; m < 4; ++m) {
    const int rbase = wr * 64 + m * 16 + lk * 4;
#pragma unroll
    for (int r = 0; r < 4; ++r) {
      const int row_l = rbase + r;
      const float xv  = (t > 0) ? xbuf[row_l] : 0.f;
      float gi = acc[m][0][r] + xv * wih[0] + bb[0];
      float gf = acc[m][1][r] + xv * wih[1] + bb[1];
      float gg = acc[m][2][r] + xv * wih[2] + bb[2];
      float go = acc[m][3][r] + xv * wih[3] + bb[3];
      const size_t idx = (size_t)(brow + row_l) * H_SZ + hcol;
      float cc = g_c[idx];
      float cn = fsig(gf) * cc + fsig(gi) * ftanh(gg);
      g_c[idx] = cn;
      hout[idx] = f2bf(fsig(go) * ftanh(cn));
    }
  }
}

// final head for t = S-1
__global__ __launch_bounds__(256)
void pred_last(const float* __restrict__ wfc, const float* __restrict__ bfc,
               float* __restrict__ out) {
  const int tid = threadIdx.x;
  const int l16 = tid & 15;
  const int row = blockIdx.x * 16 + (tid >> 4);
  const ushort* hp = g_h[0] + (size_t)row * H_SZ;  // after 128 steps h lives in buffer 0
  float acc = 0.f;
#pragma unroll
  for (int i = 0; i < 8; ++i) {
    const int k0 = i * 128 + l16 * 8;
    short8 v = *(const short8*)&hp[k0];
#pragma unroll
    for (int j = 0; j < 8; ++j) acc += bf2f((ushort)v[j]) * wfc[k0 + j];
  }
#pragma unroll
  for (int o = 8; o; o >>= 1) acc += __shfl_xor(acc, o, 64);
  if (l16 == 0) out[(size_t)row * S_SZ + (S_SZ - 1)] = acc + bfc[0];
}

extern "C" void kernel_launch(void* const* d_in, const int* in_sizes, int n_in,
                              void* d_out, int out_size, void* d_ws, size_t ws_size,
                              hipStream_t stream) {
  const float* hidden = (const float*)d_in[0];
  const float* cell   = (const float*)d_in[1];
  const float* W_ih   = (const float*)d_in[2];
  const float* W_hh   = (const float*)d_in[3];
  const float* b_ih   = (const float*)d_in[4];
  const float* b_hh   = (const float*)d_in[5];
  const float* W_fc   = (const float*)d_in[6];
  const float* b_fc   = (const float*)d_in[7];
  float* out = (float*)d_out;

  prep_wpack<<<2048, 256, 0, stream>>>(W_hh);
  prep_misc<<<16, 256, 0, stream>>>(W_ih, b_ih, b_hh);
  prep_state<<<1024, 256, 0, stream>>>(hidden, cell);

  dim3 grid(32, 16);
  for (int t = 0; t < S_SZ; ++t) {
    const int tp = (t > 0) ? (t - 1) : 0;
    lstm_step<<<grid, 256, 0, stream>>>(t, t & 1, W_fc + (size_t)tp * H_SZ,
                                        b_fc + tp, out);
  }
  pred_last<<<128, 256, 0, stream>>>(W_fc + (size_t)(S_SZ - 1) * H_SZ,
                                     b_fc + (S_SZ - 1), out);
}

// Round 2
// 4941.202 us; speedup vs baseline: 1.1849x; 1.1849x over previous
//
#include <hip/hip_runtime.h>
#include <hip/hip_bf16.h>
#include <stdint.h>

#define B_SZ 2048
#define H_SZ 1024
#define S_SZ 128
#define G4   4096
#define BK   64
#define NKK  (H_SZ / BK)  // 16 K-tiles

typedef short short8 __attribute__((ext_vector_type(8)));
typedef float floatx4 __attribute__((ext_vector_type(4)));

#define AS1 __attribute__((address_space(1)))
#define AS3 __attribute__((address_space(3)))

// Persistent device buffers (fully rewritten on every kernel_launch call).
// Global layouts for W and h are XOR-swizzled within each 128B row-chunk:
// stored elem index = k ^ ((row&7)<<3). Linear global_load_lds staging then
// yields a swizzled LDS tile; ds_read applies the same XOR -> conflict-free.
__device__ ushort g_Wp[G4 * H_SZ];       // packed W_hh bf16, row j=(h/16)*64+gate*16+(h%16), swizzled
__device__ ushort g_h[2][B_SZ * H_SZ];   // hidden bf16, swizzled cols
__device__ float  g_c[B_SZ * H_SZ];      // cell fp32, linear
__device__ float  g_wih[G4];             // packed W_ih
__device__ float  g_bias[G4];            // packed b_ih + b_hh
__device__ float  g_pp[2][32][B_SZ];     // per-jt pred partials, ping-pong by t&1

__device__ __forceinline__ float bf2f(ushort u) {
  return __uint_as_float(((unsigned)u) << 16);
}
__device__ __forceinline__ ushort f2bf(float f) {
  unsigned u = __float_as_uint(f);
  return (ushort)((u + 0x7FFFu + ((u >> 16) & 1u)) >> 16);
}
__device__ __forceinline__ float fsig(float x) { return 1.f / (1.f + __expf(-x)); }
__device__ __forceinline__ float ftanh(float x) { return 1.f - 2.f / (__expf(2.f * x) + 1.f); }

__device__ __forceinline__ void gload16(const void* g, void* l) {
  __builtin_amdgcn_global_load_lds((const AS1 void*)g, (AS3 void*)l, 16, 0, 0);
}

// ---------------- prep kernels ----------------

__global__ __launch_bounds__(256) void prep_wpack(const float* __restrict__ Whh) {
  const int gid = blockIdx.x * 256 + threadIdx.x;  // 524288
  const int j   = gid >> 7;                        // packed row 0..4095
  const int k8  = (gid & 127) << 3;                // elem offset 0..1016
  const int gate = (j >> 4) & 3;
  const int h    = ((j >> 6) << 4) | (j & 15);
  const float* src = Whh + (size_t)(gate * H_SZ + h) * H_SZ + k8;
  floatx4 a = *(const floatx4*)src;
  floatx4 b = *(const floatx4*)(src + 4);
  short8 o;
#pragma unroll
  for (int i = 0; i < 4; ++i) o[i] = (short)f2bf(a[i]);
#pragma unroll
  for (int i = 0; i < 4; ++i) o[4 + i] = (short)f2bf(b[i]);
  *(short8*)&g_Wp[(size_t)j * H_SZ + (k8 ^ ((j & 7) << 3))] = o;
}

__global__ __launch_bounds__(256) void prep_misc(const float* __restrict__ Wih,
                                                 const float* __restrict__ bih,
                                                 const float* __restrict__ bhh) {
  const int j = blockIdx.x * 256 + threadIdx.x;  // 4096
  const int gate = (j >> 4) & 3;
  const int h    = ((j >> 6) << 4) | (j & 15);
  const int jp   = gate * H_SZ + h;
  g_wih[j]  = Wih[jp];
  g_bias[j] = bih[jp] + bhh[jp];
}

__global__ __launch_bounds__(256) void prep_state(const float* __restrict__ hidden,
                                                  const float* __restrict__ cell) {
  const int gid = blockIdx.x * 256 + threadIdx.x;  // 262144
  const int row = gid >> 7;
  const int k8  = (gid & 127) << 3;
  const size_t src = (size_t)row * H_SZ + k8;
  short8 o;
#pragma unroll
  for (int i = 0; i < 8; ++i) o[i] = (short)f2bf(hidden[src + i]);
  *(short8*)&g_h[0][(size_t)row * H_SZ + (k8 ^ ((row & 7) << 3))] = o;
  floatx4 c0 = *(const floatx4*)&cell[src];
  floatx4 c1 = *(const floatx4*)&cell[src + 4];
  *(floatx4*)&g_c[src]     = c0;
  *(floatx4*)&g_c[src + 4] = c1;
}

// ---------------- main step kernel ----------------
// grid (32, 16): x = jt (128 packed gate-cols = 32 h), y = bt (128 batch rows)
__global__ __launch_bounds__(256, 2)
void lstm_step(int t, int p, const float* __restrict__ Wfc,
               const float* __restrict__ bfc, float* __restrict__ out) {
  __shared__ ushort Al[2][128 * BK];  // 2 x 16KB
  __shared__ ushort Bl[2][128 * BK];  // 2 x 16KB  (total 64KB)

  const ushort* __restrict__ hin = g_h[p];
  ushort* __restrict__ hout      = g_h[p ^ 1];

  const int tid  = threadIdx.x;
  const int lane = tid & 63;
  const int wid  = tid >> 6;
  const int jt   = blockIdx.x;
  const int brow = blockIdx.y << 7;
  const int jcol = jt << 7;
  const int wr = wid >> 1, wc = wid & 1;
  const int lr = lane & 15, lk = lane >> 4;
  const int xorv = (lr & 7) << 3;

  // staging lane geometry: each gload16 covers 8 rows x 128B
  const int srow = lane >> 3;
  const int scol = (lane & 7) << 3;
  const size_t arb = (size_t)(brow + wid * 32 + srow) * H_SZ + scol;
  const size_t brb = (size_t)(jcol + wid * 32 + srow) * H_SZ + scol;
  ushort* const ad0 = &Al[0][wid * 32 * BK];
  ushort* const ad1 = &Al[1][wid * 32 * BK];
  ushort* const bd0 = &Bl[0][wid * 32 * BK];
  ushort* const bd1 = &Bl[1][wid * 32 * BK];

  floatx4 acc[4][4];
#pragma unroll
  for (int m = 0; m < 4; ++m)
#pragma unroll
    for (int n = 0; n < 4; ++n) acc[m][n] = {0.f, 0.f, 0.f, 0.f};

  int aoff[4], boff[4];
#pragma unroll
  for (int m = 0; m < 4; ++m) aoff[m] = (wr * 64 + m * 16 + lr) * BK;
#pragma unroll
  for (int n = 0; n < 4; ++n) boff[n] = (wc * 64 + n * 16 + lr) * BK;
  const int c0 = (lk * 8) ^ xorv;
  const int c1 = (32 + lk * 8) ^ xorv;

#define STAGE(AD, BD, KO)                                                   \
  {                                                                         \
    const int ko_ = (KO) * BK;                                              \
    _Pragma("unroll") for (int i = 0; i < 4; ++i) {                         \
      gload16(hin + arb + (size_t)i * 8 * H_SZ + ko_, AD + i * 8 * BK);     \
      gload16(g_Wp + brb + (size_t)i * 8 * H_SZ + ko_, BD + i * 8 * BK);    \
    }                                                                       \
  }

#define COMPUTE(AC, BC)                                                     \
  {                                                                         \
    short8 a[4], b[4];                                                      \
    _Pragma("unroll") for (int k2 = 0; k2 < 2; ++k2) {                      \
      const int cc_ = k2 ? c1 : c0;                                         \
      _Pragma("unroll") for (int m = 0; m < 4; ++m)                         \
          a[m] = *(const short8*)&(AC)[aoff[m] + cc_];                      \
      _Pragma("unroll") for (int n = 0; n < 4; ++n)                         \
          b[n] = *(const short8*)&(BC)[boff[n] + cc_];                      \
      _Pragma("unroll") for (int m = 0; m < 4; ++m)                         \
          _Pragma("unroll") for (int n = 0; n < 4; ++n)                     \
              acc[m][n] = __builtin_amdgcn_mfma_f32_16x16x32_bf16(          \
                  a[m], b[n], acc[m][n], 0, 0, 0);                          \
    }                                                                       \
  }

  // prologue: stage tile 0 into buf0
  STAGE(ad0, bd0, 0);
  __syncthreads();

  // 2-phase pipelined K-loop, unrolled x2 so buffer index is static
  for (int kk = 0; kk < NKK; kk += 2) {
    STAGE(ad1, bd1, kk + 1);          // issue next-tile loads first
    COMPUTE(Al[0], Bl[0]);            // compute current under load latency
    __syncthreads();                  // drains vmcnt -> buf1 ready
    if (kk + 2 < NKK) STAGE(ad0, bd0, kk + 2);
    COMPUTE(Al[1], Bl[1]);
    __syncthreads();
  }

  // ---------------- epilogue ----------------
  float* predp = (float*)&Al[0][0];  // 256 floats (reuse LDS)
  float* xbuf  = (float*)&Bl[0][0];  // 128 floats

  if (t > 0 && tid < 128) {
    float s = 0.f;
#pragma unroll
    for (int j = 0; j < 32; ++j) s += g_pp[(t - 1) & 1][j][brow + tid];
    s += bfc[t - 1];
    xbuf[tid] = s;
    if (jt == 0) out[(size_t)(brow + tid) * S_SZ + (t - 1)] = s;
  }
  __syncthreads();

  const int hcol = ((jt * 2 + wc) << 4) + lr;       // global h index
  const float wfc_l = Wfc[(size_t)t * H_SZ + hcol]; // own-step head weight
  float wih[4], bb[4];
#pragma unroll
  for (int n = 0; n < 4; ++n) {
    const int col = jcol + wc * 64 + n * 16 + lr;
    wih[n] = g_wih[col];
    bb[n]  = g_bias[col];
  }

#pragma unroll
  for (int m = 0; m < 4; ++m) {
#pragma unroll
    for (int r = 0; r < 4; ++r) {
      const int row_l = wr * 64 + m * 16 + lk * 4 + r;
      const float xv = (t > 0) ? xbuf[row_l] : 0.f;
      float gi = acc[m][0][r] + xv * wih[0] + bb[0];
      float gf = acc[m][1][r] + xv * wih[1] + bb[1];
      float gg = acc[m][2][r] + xv * wih[2] + bb[2];
      float go = acc[m][3][r] + xv * wih[3] + bb[3];
      const int row = brow + row_l;
      const size_t cidx = (size_t)row * H_SZ + hcol;
      float cc = g_c[cidx];
      float cn = fsig(gf) * cc + fsig(gi) * ftanh(gg);
      g_c[cidx] = cn;
      float hv = fsig(go) * ftanh(cn);
      hout[(size_t)row * H_SZ + (hcol ^ ((row_l & 7) << 3))] = f2bf(hv);
      // own-step head partial: pred_t[row] += h_t[row,hcol] * Wfc[t,hcol]
      float pp = hv * wfc_l;
      pp += __shfl_xor(pp, 1);
      pp += __shfl_xor(pp, 2);
      pp += __shfl_xor(pp, 4);
      pp += __shfl_xor(pp, 8);
      if (lr == 0) predp[wc * 128 + row_l] = pp;
    }
  }
  __syncthreads();
  if (tid < 128) g_pp[t & 1][jt][brow + tid] = predp[tid] + predp[128 + tid];
#undef STAGE
#undef COMPUTE
}

// final head output for t = S-1 (partials already in g_pp[1])
__global__ __launch_bounds__(256)
void pred_last(const float* __restrict__ bfc, float* __restrict__ out) {
  const int row = blockIdx.x * 256 + threadIdx.x;  // 2048 rows
  float s = 0.f;
#pragma unroll
  for (int j = 0; j < 32; ++j) s += g_pp[1][j][row];
  out[(size_t)row * S_SZ + (S_SZ - 1)] = s + bfc[S_SZ - 1];
}

extern "C" void kernel_launch(void* const* d_in, const int* in_sizes, int n_in,
                              void* d_out, int out_size, void* d_ws, size_t ws_size,
                              hipStream_t stream) {
  const float* hidden = (const float*)d_in[0];
  const float* cell   = (const float*)d_in[1];
  const float* W_ih   = (const float*)d_in[2];
  const float* W_hh   = (const float*)d_in[3];
  const float* b_ih   = (const float*)d_in[4];
  const float* b_hh   = (const float*)d_in[5];
  const float* W_fc   = (const float*)d_in[6];
  const float* b_fc   = (const float*)d_in[7];
  float* out = (float*)d_out;

  prep_wpack<<<2048, 256, 0, stream>>>(W_hh);
  prep_misc<<<16, 256, 0, stream>>>(W_ih, b_ih, b_hh);
  prep_state<<<1024, 256, 0, stream>>>(hidden, cell);

  dim3 grid(32, 16);
  for (int t = 0; t < S_SZ; ++t) {
    lstm_step<<<grid, 256, 0, stream>>>(t, t & 1, W_fc, b_fc, out);
  }
  pred_last<<<8, 256, 0, stream>>>(b_fc, out);
}

// Round 3
// 4817.786 us; speedup vs baseline: 1.2153x; 1.0256x over previous
//
#include <hip/hip_runtime.h>
#include <hip/hip_bf16.h>
#include <stdint.h>

#define B_SZ 2048
#define H_SZ 1024
#define S_SZ 128
#define G4   4096
#define BK   64
#define NKK  (H_SZ / BK)  // 16 K-tiles

typedef short short8 __attribute__((ext_vector_type(8)));
typedef float floatx4 __attribute__((ext_vector_type(4)));

#define AS1 __attribute__((address_space(1)))
#define AS3 __attribute__((address_space(3)))

// Persistent device buffers (fully rewritten on every kernel_launch call).
// Global layouts for W and h are XOR-swizzled within each 128B row-chunk:
// stored elem index = k ^ ((row&7)<<3). Linear global_load_lds staging then
// yields a swizzled LDS tile; ds_read applies the same XOR -> conflict-free.
__device__ ushort g_Wp[G4 * H_SZ];       // packed W_hh bf16, row j=(h/16)*64+gate*16+(h%16), swizzled
__device__ ushort g_h[2][B_SZ * H_SZ];   // hidden bf16, swizzled cols
__device__ float  g_c[B_SZ * H_SZ];      // cell fp32, linear
__device__ float  g_wih[G4];             // packed W_ih
__device__ float  g_bias[G4];            // packed b_ih + b_hh
__device__ float  g_pp[2][32][B_SZ];     // per-jt pred partials, ping-pong by t&1

__device__ __forceinline__ float bf2f(ushort u) {
  return __uint_as_float(((unsigned)u) << 16);
}
__device__ __forceinline__ ushort f2bf(float f) {
  unsigned u = __float_as_uint(f);
  return (ushort)((u + 0x7FFFu + ((u >> 16) & 1u)) >> 16);
}
__device__ __forceinline__ float fsig(float x) { return 1.f / (1.f + __expf(-x)); }
__device__ __forceinline__ float ftanh(float x) { return 1.f - 2.f / (__expf(2.f * x) + 1.f); }

__device__ __forceinline__ void gload16(const void* g, void* l) {
  __builtin_amdgcn_global_load_lds((const AS1 void*)g, (AS3 void*)l, 16, 0, 0);
}

// ---------------- prep kernels ----------------

__global__ __launch_bounds__(256) void prep_wpack(const float* __restrict__ Whh) {
  const int gid = blockIdx.x * 256 + threadIdx.x;  // 524288
  const int j   = gid >> 7;                        // packed row 0..4095
  const int k8  = (gid & 127) << 3;                // elem offset 0..1016
  const int gate = (j >> 4) & 3;
  const int h    = ((j >> 6) << 4) | (j & 15);
  const float* src = Whh + (size_t)(gate * H_SZ + h) * H_SZ + k8;
  floatx4 a = *(const floatx4*)src;
  floatx4 b = *(const floatx4*)(src + 4);
  short8 o;
#pragma unroll
  for (int i = 0; i < 4; ++i) o[i] = (short)f2bf(a[i]);
#pragma unroll
  for (int i = 0; i < 4; ++i) o[4 + i] = (short)f2bf(b[i]);
  *(short8*)&g_Wp[(size_t)j * H_SZ + (k8 ^ ((j & 7) << 3))] = o;
}

__global__ __launch_bounds__(256) void prep_misc(const float* __restrict__ Wih,
                                                 const float* __restrict__ bih,
                                                 const float* __restrict__ bhh) {
  const int j = blockIdx.x * 256 + threadIdx.x;  // 4096
  const int gate = (j >> 4) & 3;
  const int h    = ((j >> 6) << 4) | (j & 15);
  const int jp   = gate * H_SZ + h;
  g_wih[j]  = Wih[jp];
  g_bias[j] = bih[jp] + bhh[jp];
}

__global__ __launch_bounds__(256) void prep_state(const float* __restrict__ hidden,
                                                  const float* __restrict__ cell) {
  const int gid = blockIdx.x * 256 + threadIdx.x;  // 262144
  const int row = gid >> 7;
  const int k8  = (gid & 127) << 3;
  const size_t src = (size_t)row * H_SZ + k8;
  short8 o;
#pragma unroll
  for (int i = 0; i < 8; ++i) o[i] = (short)f2bf(hidden[src + i]);
  *(short8*)&g_h[0][(size_t)row * H_SZ + (k8 ^ ((row & 7) << 3))] = o;
  floatx4 c0 = *(const floatx4*)&cell[src];
  floatx4 c1 = *(const floatx4*)&cell[src + 4];
  *(floatx4*)&g_c[src]     = c0;
  *(floatx4*)&g_c[src + 4] = c1;
}

// ---------------- main step kernel ----------------
// grid 512 (1D). XCD-aware decomposition: hardware assigns XCD = bid % 8
// (round-robin). We map so XCD x owns jt in {4x..4x+3} (its W panels = 1MB,
// L2-resident) and all 16 bt slices (4 co-resident blocks share each h tile).
__global__ __launch_bounds__(256, 2)
void lstm_step(int t, int p, const float* __restrict__ Wfc,
               const float* __restrict__ bfc, float* __restrict__ out) {
  __shared__ ushort Al[2][128 * BK];  // 2 x 16KB
  __shared__ ushort Bl[2][128 * BK];  // 2 x 16KB  (total 64KB)

  const ushort* __restrict__ hin = g_h[p];
  ushort* __restrict__ hout      = g_h[p ^ 1];

  const int tid  = threadIdx.x;
  const int lane = tid & 63;
  const int wid  = tid >> 6;
  const int bid  = blockIdx.x;
  const int xcd  = bid & 7;
  const int idx  = bid >> 3;                 // 0..63 within XCD
  const int jt   = (xcd << 2) | (idx & 3);   // 4 consecutive W panels per XCD
  const int bt   = idx >> 2;                 // all 16 batch slices per XCD
  const int brow = bt << 7;
  const int jcol = jt << 7;
  const int wr = wid >> 1, wc = wid & 1;
  const int lr = lane & 15, lk = lane >> 4;
  const int xorv = (lr & 7) << 3;

  // staging lane geometry: each gload16 covers 8 rows x 128B
  const int srow = lane >> 3;
  const int scol = (lane & 7) << 3;
  const size_t arb = (size_t)(brow + wid * 32 + srow) * H_SZ + scol;
  const size_t brb = (size_t)(jcol + wid * 32 + srow) * H_SZ + scol;
  ushort* const ad0 = &Al[0][wid * 32 * BK];
  ushort* const ad1 = &Al[1][wid * 32 * BK];
  ushort* const bd0 = &Bl[0][wid * 32 * BK];
  ushort* const bd1 = &Bl[1][wid * 32 * BK];

  floatx4 acc[4][4];
#pragma unroll
  for (int m = 0; m < 4; ++m)
#pragma unroll
    for (int n = 0; n < 4; ++n) acc[m][n] = {0.f, 0.f, 0.f, 0.f};

  int aoff[4], boff[4];
#pragma unroll
  for (int m = 0; m < 4; ++m) aoff[m] = (wr * 64 + m * 16 + lr) * BK;
#pragma unroll
  for (int n = 0; n < 4; ++n) boff[n] = (wc * 64 + n * 16 + lr) * BK;
  const int c0 = (lk * 8) ^ xorv;
  const int c1 = (32 + lk * 8) ^ xorv;

#define STAGE(AD, BD, KO)                                                   \
  {                                                                         \
    const int ko_ = (KO) * BK;                                              \
    _Pragma("unroll") for (int i = 0; i < 4; ++i) {                         \
      gload16(hin + arb + (size_t)i * 8 * H_SZ + ko_, AD + i * 8 * BK);     \
      gload16(g_Wp + brb + (size_t)i * 8 * H_SZ + ko_, BD + i * 8 * BK);    \
    }                                                                       \
  }

#define COMPUTE(AC, BC)                                                     \
  {                                                                         \
    short8 a[4], b[4];                                                      \
    _Pragma("unroll") for (int k2 = 0; k2 < 2; ++k2) {                      \
      const int cc_ = k2 ? c1 : c0;                                         \
      _Pragma("unroll") for (int m = 0; m < 4; ++m)                         \
          a[m] = *(const short8*)&(AC)[aoff[m] + cc_];                      \
      _Pragma("unroll") for (int n = 0; n < 4; ++n)                         \
          b[n] = *(const short8*)&(BC)[boff[n] + cc_];                      \
      _Pragma("unroll") for (int m = 0; m < 4; ++m)                         \
          _Pragma("unroll") for (int n = 0; n < 4; ++n)                     \
              acc[m][n] = __builtin_amdgcn_mfma_f32_16x16x32_bf16(          \
                  a[m], b[n], acc[m][n], 0, 0, 0);                          \
    }                                                                       \
  }

  // prologue: stage tile 0 into buf0
  STAGE(ad0, bd0, 0);
  __syncthreads();

  // 2-phase pipelined K-loop, unrolled x2 so buffer index is static
  for (int kk = 0; kk < NKK; kk += 2) {
    STAGE(ad1, bd1, kk + 1);          // issue next-tile loads first
    COMPUTE(Al[0], Bl[0]);            // compute current under load latency
    __syncthreads();                  // drains vmcnt -> buf1 ready
    if (kk + 2 < NKK) STAGE(ad0, bd0, kk + 2);
    COMPUTE(Al[1], Bl[1]);
    __syncthreads();
  }

  // ---------------- epilogue ----------------
  float* predp = (float*)&Al[0][0];  // 256 floats (reuse LDS)
  float* xbuf  = (float*)&Bl[0][0];  // 128 floats

  if (t > 0 && tid < 128) {
    float s = 0.f;
#pragma unroll
    for (int j = 0; j < 32; ++j) s += g_pp[(t - 1) & 1][j][brow + tid];
    s += bfc[t - 1];
    xbuf[tid] = s;
    if (jt == 0) out[(size_t)(brow + tid) * S_SZ + (t - 1)] = s;
  }
  __syncthreads();

  const int hcol = ((jt * 2 + wc) << 4) + lr;       // global h index
  const float wfc_l = Wfc[(size_t)t * H_SZ + hcol]; // own-step head weight
  float wih[4], bb[4];
#pragma unroll
  for (int n = 0; n < 4; ++n) {
    const int col = jcol + wc * 64 + n * 16 + lr;
    wih[n] = g_wih[col];
    bb[n]  = g_bias[col];
  }

#pragma unroll
  for (int m = 0; m < 4; ++m) {
#pragma unroll
    for (int r = 0; r < 4; ++r) {
      const int row_l = wr * 64 + m * 16 + lk * 4 + r;
      const float xv = (t > 0) ? xbuf[row_l] : 0.f;
      float gi = acc[m][0][r] + xv * wih[0] + bb[0];
      float gf = acc[m][1][r] + xv * wih[1] + bb[1];
      float gg = acc[m][2][r] + xv * wih[2] + bb[2];
      float go = acc[m][3][r] + xv * wih[3] + bb[3];
      const int row = brow + row_l;
      const size_t cidx = (size_t)row * H_SZ + hcol;
      float cc = g_c[cidx];
      float cn = fsig(gf) * cc + fsig(gi) * ftanh(gg);
      g_c[cidx] = cn;
      float hv = fsig(go) * ftanh(cn);
      hout[(size_t)row * H_SZ + (hcol ^ ((row_l & 7) << 3))] = f2bf(hv);
      // own-step head partial: pred_t[row] += h_t[row,hcol] * Wfc[t,hcol]
      float pp = hv * wfc_l;
      pp += __shfl_xor(pp, 1);
      pp += __shfl_xor(pp, 2);
      pp += __shfl_xor(pp, 4);
      pp += __shfl_xor(pp, 8);
      if (lr == 0) predp[wc * 128 + row_l] = pp;
    }
  }
  __syncthreads();
  if (tid < 128) g_pp[t & 1][jt][brow + tid] = predp[tid] + predp[128 + tid];
#undef STAGE
#undef COMPUTE
}

// final head output for t = S-1 (partials already in g_pp[1])
__global__ __launch_bounds__(256)
void pred_last(const float* __restrict__ bfc, float* __restrict__ out) {
  const int row = blockIdx.x * 256 + threadIdx.x;  // 2048 rows
  float s = 0.f;
#pragma unroll
  for (int j = 0; j < 32; ++j) s += g_pp[1][j][row];
  out[(size_t)row * S_SZ + (S_SZ - 1)] = s + bfc[S_SZ - 1];
}

extern "C" void kernel_launch(void* const* d_in, const int* in_sizes, int n_in,
                              void* d_out, int out_size, void* d_ws, size_t ws_size,
                              hipStream_t stream) {
  const float* hidden = (const float*)d_in[0];
  const float* cell   = (const float*)d_in[1];
  const float* W_ih   = (const float*)d_in[2];
  const float* W_hh   = (const float*)d_in[3];
  const float* b_ih   = (const float*)d_in[4];
  const float* b_hh   = (const float*)d_in[5];
  const float* W_fc   = (const float*)d_in[6];
  const float* b_fc   = (const float*)d_in[7];
  float* out = (float*)d_out;

  prep_wpack<<<2048, 256, 0, stream>>>(W_hh);
  prep_misc<<<16, 256, 0, stream>>>(W_ih, b_ih, b_hh);
  prep_state<<<1024, 256, 0, stream>>>(hidden, cell);

  for (int t = 0; t < S_SZ; ++t) {
    lstm_step<<<512, 256, 0, stream>>>(t, t & 1, W_fc, b_fc, out);
  }
  pred_last<<<8, 256, 0, stream>>>(b_fc, out);
}